// Round 4
// baseline (363.983 us; speedup 1.0000x reference)
//
#include <hip/hip_runtime.h>
#include <hip/hip_bf16.h>
#include <stdint.h>

#define NB 16
#define JXX 4096
#define JQQ 512
#define DDD 256
#define LOG2E 1.44269504f

typedef __attribute__((ext_vector_type(8))) _Float16 f16x8;
typedef __attribute__((ext_vector_type(4))) _Float16 f16x4;
typedef __attribute__((ext_vector_type(4))) float f32x4;

__device__ __forceinline__ uint16_t f2h(float f) {
    union { _Float16 h; uint16_t s; } u; u.h = (_Float16)f; return u.s;
}

// ---------------- mask canonicalization (dtype-detecting) ----------------
__global__ void k_mask(const void* cmask, const void* qmask,
                       uint8_t* cm8, uint8_t* qm8) {
    int i = blockIdx.x * 256 + threadIdx.x;
    uint32_t w0c = *(const uint32_t*)cmask;
    uint32_t w0q = *(const uint32_t*)qmask;
    int mc = (w0c == 1u) ? 1 : (w0c == 0x3f800000u ? 2 : 0);
    int mq = (w0q == 1u) ? 1 : (w0q == 0x3f800000u ? 2 : 0);
    if (i < NB * JXX) {
        uint8_t v;
        if (mc == 1)      v = ((const int*)cmask)[i] != 0;
        else if (mc == 2) v = ((const float*)cmask)[i] != 0.0f;
        else              v = ((const uint8_t*)cmask)[i] != 0;
        cm8[i] = v;
    }
    if (i < NB * JQQ) {
        uint8_t v;
        if (mq == 1)      v = ((const int*)qmask)[i] != 0;
        else if (mq == 2) v = ((const float*)qmask)[i] != 0.0f;
        else              v = ((const uint8_t*)qmask)[i] != 0;
        qm8[i] = v;
    }
}

// ---- prep q: f32 [B][JQ][D] -> f16 [B][JQ][D] (straight) + f16 [B][D][JQ] (T) ----
__global__ void k_prep_q(const float* __restrict__ qg,
                         uint16_t* __restrict__ q16,
                         uint16_t* __restrict__ qT16) {
    __shared__ float tile[64][65];
    const int b = blockIdx.z, j0 = blockIdx.x * 64, d0 = blockIdx.y * 64;
    const int t = threadIdx.x;
    #pragma unroll
    for (int i = 0; i < 16; i++) {
        int e = t + 256 * i;
        int r = e >> 6, c = e & 63;
        float v = qg[((long)b * JQQ + j0 + r) * DDD + d0 + c];
        tile[r][c] = v;
        q16[((long)b * JQQ + j0 + r) * DDD + d0 + c] = f2h(v);
    }
    __syncthreads();
    #pragma unroll
    for (int i = 0; i < 16; i++) {
        int e = t + 256 * i;
        int c = e >> 6, r = e & 63;
        qT16[((long)b * DDD + d0 + c) * JQQ + j0 + r] = f2h(tile[r][c]);
    }
}

// ---- prep W: f32 [1024][256] (k,n) -> packed f16 frags WP[kt][nt][lane][8] ----
// element (k = kt*32 + g*8 + i, n = nt*16 + l15) at WP[((kt*16+nt)*64 + g*16+l15)*8 + i]
__global__ void k_prep_w(const float* __restrict__ Wr, const float* __restrict__ Wg,
                         uint16_t* __restrict__ WrP, uint16_t* __restrict__ WgP) {
    __shared__ _Float16 tile[32 * 264];
    const float* W = blockIdx.y ? Wg : Wr;
    uint16_t* WP = blockIdx.y ? WgP : WrP;
    const int kt = blockIdx.x, t = threadIdx.x;
    #pragma unroll
    for (int i = 0; i < 32; i++) {
        int e = t + 256 * i;
        int r = e >> 8, c = e & 255;
        tile[r * 264 + c] = (_Float16)W[(long)(kt * 32 + r) * 256 + c];
    }
    __syncthreads();
    #pragma unroll
    for (int ss = 0; ss < 4; ss++) {
        int slot = ss * 256 + t;             // 0..1023 = nt*64 + lane
        int nt = slot >> 6, lane = slot & 63;
        int gg = lane >> 4, l = lane & 15;
        f16x8 v;
        #pragma unroll
        for (int i = 0; i < 8; i++) v[i] = tile[(gg * 8 + i) * 264 + nt * 16 + l];
        *(f16x8*)(WP + ((long)(kt * 16 + nt) * 64 + lane) * 8) = v;
    }
}

// ---------------- fused attention v2: barrier-free, cache-direct fragments ----------------
// grid (JX/64, B), 256 thr, 4 independent waves. wave = 16 x-rows; j in tiles of 32.
// Logits mfma: D[j][x], x = lane&15. PV mfma (swapped): D[d][x], x = lane&15.
__global__ __launch_bounds__(256) void k_attn(
    const float* __restrict__ cg,
    const uint16_t* __restrict__ q16,   // [B][JQ][D] f16
    const uint16_t* __restrict__ qT16,  // [B][D][JQ] f16
    const uint8_t* __restrict__ cm8,
    const uint8_t* __restrict__ qm8,
    uint16_t* __restrict__ qa16)        // [B][JX][D] f16
{
    __shared__ __align__(16) uint16_t P_lds[4 * 16 * 40];  // per-wave [x][j] pitch 40

    const int b = blockIdx.y;
    const int t = threadIdx.x;
    const int wave = t >> 6;
    const int lane = t & 63;
    const int l15 = lane & 15;
    const int g = lane >> 4;
    const int xw = blockIdx.x * 64 + wave * 16;

    // c fragments (B operand of logits mfma), resident for whole kernel
    f16x8 cfrag[8];
    {
        const float* crow = cg + ((long)b * JXX + xw + l15) * DDD;
        #pragma unroll
        for (int kb = 0; kb < 8; kb++) {
            float4 v0 = *(const float4*)(crow + kb * 32 + g * 8);
            float4 v1 = *(const float4*)(crow + kb * 32 + g * 8 + 4);
            f16x8 f;
            f[0] = (_Float16)v0.x; f[1] = (_Float16)v0.y; f[2] = (_Float16)v0.z; f[3] = (_Float16)v0.w;
            f[4] = (_Float16)v1.x; f[5] = (_Float16)v1.y; f[6] = (_Float16)v1.z; f[7] = (_Float16)v1.w;
            cfrag[kb] = f;
        }
    }
    const bool cvalid = cm8[(long)b * JXX + xw + l15] != 0;
    float m_run = cvalid ? -1e30f : 0.0f;
    float s_run = 0.0f;
    const f32x4 fzero = {0.f, 0.f, 0.f, 0.f};
    f32x4 qa[16];   // qa[dt][r] = q_a^T[d = dt*16 + g*4 + r][x = l15]
    #pragma unroll
    for (int i = 0; i < 16; i++) qa[i] = fzero;

    const uint16_t* qb  = q16  + (long)b * JQQ * DDD;
    const uint16_t* qTb = qT16 + (long)b * DDD * JQQ;
    const uint8_t*  qmb = qm8  + (long)b * JQQ;

    for (int jt = 0; jt < 16; jt++) {
        uint32_t qmw0 = *(const uint32_t*)(qmb + jt * 32 + g * 4);
        uint32_t qmw1 = *(const uint32_t*)(qmb + jt * 32 + 16 + g * 4);

        // ---- logits: D[j][x], A-frags straight from L1/L2 ----
        f32x4 acc[2];
        #pragma unroll
        for (int js = 0; js < 2; js++) {
            f32x4 a = fzero;
            const uint16_t* qrow = qb + (long)(jt * 32 + js * 16 + l15) * DDD + g * 8;
            #pragma unroll
            for (int kb = 0; kb < 8; kb++) {
                f16x8 qf = *(const f16x8*)(qrow + kb * 32);
                a = __builtin_amdgcn_mfma_f32_16x16x32_f16(qf, cfrag[kb], a, 0, 0, 0);
            }
            acc[js] = a;
        }

        // ---- online softmax over this 32-j chunk (state per x = l15) ----
        float lmax = -1e30f;
        #pragma unroll
        for (int r = 0; r < 4; r++) {
            bool qv0 = (qmw0 >> (8 * r)) & 0xffu;
            bool qv1 = (qmw1 >> (8 * r)) & 0xffu;
            lmax = fmaxf(lmax, qv0 ? acc[0][r] : -1e30f);
            lmax = fmaxf(lmax, qv1 ? acc[1][r] : -1e30f);
        }
        lmax = fmaxf(lmax, __shfl_xor(lmax, 16));
        lmax = fmaxf(lmax, __shfl_xor(lmax, 32));
        float m_new = cvalid ? fmaxf(m_run, lmax) : 0.0f;
        float fsc = exp2f((m_run - m_new) * LOG2E);
        float psum = 0.0f;
        _Float16 ph[8];
        #pragma unroll
        for (int js = 0; js < 2; js++) {
            uint32_t qmw = js ? qmw1 : qmw0;
            #pragma unroll
            for (int r = 0; r < 4; r++) {
                bool qv = (qmw >> (8 * r)) & 0xffu;
                float p = qv ? exp2f((acc[js][r] - m_new) * LOG2E) : 0.0f;
                if (!cvalid) p = 1.0f;   // c-invalid row: uniform over ALL j
                psum += p;
                ph[js * 4 + r] = (_Float16)p;
            }
        }
        if (!__all(fsc == 1.0f)) {
            s_run *= fsc;
            #pragma unroll
            for (int i = 0; i < 16; i++) {
                qa[i][0] *= fsc; qa[i][1] *= fsc; qa[i][2] *= fsc; qa[i][3] *= fsc;
            }
        }
        s_run += psum;
        m_run = m_new;

        // ---- P re-layout via per-wave LDS (no barrier: wave-private) ----
        uint16_t* Pw = P_lds + wave * 640 + l15 * 40;
        f16x4 pv0, pv1;
        pv0[0] = ph[0]; pv0[1] = ph[1]; pv0[2] = ph[2]; pv0[3] = ph[3];
        pv1[0] = ph[4]; pv1[1] = ph[5]; pv1[2] = ph[6]; pv1[3] = ph[7];
        *(f16x4*)(Pw + g * 4) = pv0;
        *(f16x4*)(Pw + 16 + g * 4) = pv1;
        // pa: B-operand, B[k=j][col=x]: lane holds P[x=l15][j=g*8+i]
        f16x8 pa = *(const f16x8*)(P_lds + wave * 640 + l15 * 40 + g * 8);

        // ---- PV: A-frags straight from L1/L2 (qT rows are d-major) ----
        #pragma unroll
        for (int dt = 0; dt < 16; dt++) {
            f16x8 bq = *(const f16x8*)(qTb + (long)(dt * 16 + l15) * JQQ + jt * 32 + g * 8);
            qa[dt] = __builtin_amdgcn_mfma_f32_16x16x32_f16(bq, pa, qa[dt], 0, 0, 0);
        }
    }

    // ---- finalize: divide by per-x sum (per-lane), store fp16 q_a ----
    float s_tot = s_run + __shfl_xor(s_run, 16);
    s_tot = s_tot + __shfl_xor(s_tot, 32);
    float inv = 1.0f / s_tot;
    uint16_t* outp = qa16 + ((long)b * JXX + xw + l15) * DDD;
    #pragma unroll
    for (int dt = 0; dt < 16; dt++) {
        f16x4 v;
        v[0] = (_Float16)(qa[dt][0] * inv);
        v[1] = (_Float16)(qa[dt][1] * inv);
        v[2] = (_Float16)(qa[dt][2] * inv);
        v[3] = (_Float16)(qa[dt][3] * inv);
        *(f16x4*)(outp + dt * 16 + g * 4) = v;
    }
}

// ---------------- fused SFU v2: direct packed-W frags, (dt,kb)-major K loop ----------------
// grid (M/64, 2), 256 thr. A-frag (cf,qf) read once per (dt,kb,mf), reused by 4 comps.
__global__ __launch_bounds__(256) void k_sfu(
    const float* __restrict__ cg,
    const uint16_t* __restrict__ qa16,
    const uint16_t* __restrict__ WrP,   // packed frag layout
    const uint16_t* __restrict__ WgP,
    const float* __restrict__ Brb,
    const float* __restrict__ Bgb,
    float* __restrict__ outg)
{
    __shared__ __align__(16) uint16_t c_lds[64 * 72];
    __shared__ __align__(16) uint16_t qa_lds[64 * 72];

    const int t = threadIdx.x;
    const int wave = t >> 6;
    const int lane = t & 63;
    const int l15 = lane & 15, g = lane >> 4;
    const int mw = wave & 1, nw = wave >> 1;
    const long m0 = (long)blockIdx.x * 64;
    const int n0 = blockIdx.y * 128;
    const int ntg0 = (n0 >> 4) + nw * 4;

    const f32x4 fzero = {0.f, 0.f, 0.f, 0.f};
    f32x4 accR[2][4], accG[2][4];
    #pragma unroll
    for (int a = 0; a < 2; a++)
        #pragma unroll
        for (int bq = 0; bq < 4; bq++) { accR[a][bq] = fzero; accG[a][bq] = fzero; }

    for (int dt = 0; dt < 4; dt++) {
        __syncthreads();
        // stage raw c (f32->f16) and qa (f16 copy) for this d-range
        #pragma unroll
        for (int i = 0; i < 2; i++) {
            int idx = t + 256 * i;
            int row = idx >> 3, c8 = idx & 7;
            const float* p = cg + (m0 + row) * DDD + dt * 64 + c8 * 8;
            float4 v0 = *(const float4*)p;
            float4 v1 = *(const float4*)(p + 4);
            f16x8 f;
            f[0] = (_Float16)v0.x; f[1] = (_Float16)v0.y; f[2] = (_Float16)v0.z; f[3] = (_Float16)v0.w;
            f[4] = (_Float16)v1.x; f[5] = (_Float16)v1.y; f[6] = (_Float16)v1.z; f[7] = (_Float16)v1.w;
            *(f16x8*)(c_lds + row * 72 + c8 * 8) = f;
            *(f16x8*)(qa_lds + row * 72 + c8 * 8) =
                *(const f16x8*)(qa16 + (m0 + row) * DDD + dt * 64 + c8 * 8);
        }
        __syncthreads();
        #pragma unroll
        for (int kb = 0; kb < 2; kb++) {
            f16x8 af[4][2];
            #pragma unroll
            for (int mf = 0; mf < 2; mf++) {
                int row = mw * 32 + mf * 16 + l15;
                f16x8 cf = *(const f16x8*)(c_lds + row * 72 + kb * 32 + g * 8);
                f16x8 qf = *(const f16x8*)(qa_lds + row * 72 + kb * 32 + g * 8);
                af[0][mf] = cf;
                af[1][mf] = qf;
                af[2][mf] = cf * qf;   // packed f16
                af[3][mf] = cf - qf;
            }
            #pragma unroll
            for (int comp = 0; comp < 4; comp++) {
                int kt = comp * 8 + dt * 2 + kb;
                #pragma unroll
                for (int nt = 0; nt < 4; nt++) {
                    long slot = ((long)(kt * 16 + ntg0 + nt) * 64 + lane) * 8;
                    f16x8 br = *(const f16x8*)(WrP + slot);
                    f16x8 bg = *(const f16x8*)(WgP + slot);
                    #pragma unroll
                    for (int mf = 0; mf < 2; mf++) {
                        accR[mf][nt] = __builtin_amdgcn_mfma_f32_16x16x32_f16(af[comp][mf], br, accR[mf][nt], 0, 0, 0);
                        accG[mf][nt] = __builtin_amdgcn_mfma_f32_16x16x32_f16(af[comp][mf], bg, accG[mf][nt], 0, 0, 0);
                    }
                }
            }
        }
    }
    // epilogue: D row = g*4 + r (m), col = l15 (n)
    #pragma unroll
    for (int nt = 0; nt < 4; nt++) {
        int n = n0 + nw * 64 + nt * 16 + l15;
        float br = Brb[n], bg = Bgb[n];
        #pragma unroll
        for (int mf = 0; mf < 2; mf++) {
            long rowb = m0 + mw * 32 + mf * 16 + g * 4;
            #pragma unroll
            for (int r = 0; r < 4; r++) {
                float pr = accR[mf][nt][r] + br;
                float pg = accG[mf][nt][r] + bg;
                float x = fminf(fmaxf(pr, -30.f), 30.f);
                float e2 = __expf(2.f * x);
                float rr = (e2 - 1.f) / (e2 + 1.f);
                float gv = 1.0f / (1.0f + __expf(-pg));
                float cv = cg[(rowb + r) * DDD + n];
                outg[(rowb + r) * DDD + n] = gv * rr + (1.f - gv) * cv;
            }
        }
    }
}

extern "C" void kernel_launch(void* const* d_in, const int* in_sizes, int n_in,
                              void* d_out, int out_size, void* d_ws, size_t ws_size,
                              hipStream_t stream) {
    const float* c  = (const float*)d_in[0];
    const float* q  = (const float*)d_in[1];
    const float* Wr = (const float*)d_in[2];
    const float* Br = (const float*)d_in[3];
    const float* Wg = (const float*)d_in[4];
    const float* Bg = (const float*)d_in[5];
    const void* cmask = d_in[6];
    const void* qmask = d_in[7];

    char* ws = (char*)d_ws;
    uint16_t* q16   = (uint16_t*)(ws + 0);          //  4,194,304 B
    uint16_t* qT16  = (uint16_t*)(ws + 4194304);    //  4,194,304 B
    uint16_t* qa16  = (uint16_t*)(ws + 8388608);    // 33,554,432 B
    uint16_t* WrP   = (uint16_t*)(ws + 41943040);   //    524,288 B
    uint16_t* WgP   = (uint16_t*)(ws + 42467328);   //    524,288 B
    uint8_t*  cm8   = (uint8_t*)(ws + 42991616);    //     65,536 B
    uint8_t*  qm8   = (uint8_t*)(ws + 43057152);    //      8,192 B
    (void)in_sizes; (void)n_in; (void)out_size; (void)ws_size;

    k_mask<<<dim3((NB * JXX + 255) / 256), dim3(256), 0, stream>>>(cmask, qmask, cm8, qm8);
    k_prep_q<<<dim3(8, 4, NB), dim3(256), 0, stream>>>(q, q16, qT16);
    k_prep_w<<<dim3(32, 2), dim3(256), 0, stream>>>(Wr, Wg, WrP, WgP);
    k_attn<<<dim3(JXX / 64, NB), dim3(256), 0, stream>>>(c, q16, qT16, cm8, qm8, qa16);
    k_sfu<<<dim3((NB * JXX) / 64, 2), dim3(256), 0, stream>>>(
        c, qa16, WrP, WgP, Br, Bg, (float*)d_out);
}

// Round 5
// 363.422 us; speedup vs baseline: 1.0015x; 1.0015x over previous
//
#include <hip/hip_runtime.h>
#include <hip/hip_bf16.h>
#include <stdint.h>

#define NB 16
#define JXX 4096
#define JQQ 512
#define DDD 256
#define LOG2E 1.44269504f

typedef __attribute__((ext_vector_type(8))) _Float16 f16x8;
typedef __attribute__((ext_vector_type(4))) _Float16 f16x4;
typedef __attribute__((ext_vector_type(4))) float f32x4;

__device__ __forceinline__ uint16_t f2h(float f) {
    union { _Float16 h; uint16_t s; } u; u.h = (_Float16)f; return u.s;
}

// ---------------- mask canonicalization (dtype-detecting) ----------------
__global__ void k_mask(const void* cmask, const void* qmask,
                       uint8_t* cm8, uint8_t* qm8) {
    int i = blockIdx.x * 256 + threadIdx.x;
    uint32_t w0c = *(const uint32_t*)cmask;
    uint32_t w0q = *(const uint32_t*)qmask;
    int mc = (w0c == 1u) ? 1 : (w0c == 0x3f800000u ? 2 : 0);
    int mq = (w0q == 1u) ? 1 : (w0q == 0x3f800000u ? 2 : 0);
    if (i < NB * JXX) {
        uint8_t v;
        if (mc == 1)      v = ((const int*)cmask)[i] != 0;
        else if (mc == 2) v = ((const float*)cmask)[i] != 0.0f;
        else              v = ((const uint8_t*)cmask)[i] != 0;
        cm8[i] = v;
    }
    if (i < NB * JQQ) {
        uint8_t v;
        if (mq == 1)      v = ((const int*)qmask)[i] != 0;
        else if (mq == 2) v = ((const float*)qmask)[i] != 0.0f;
        else              v = ((const uint8_t*)qmask)[i] != 0;
        qm8[i] = v;
    }
}

// ---- prep q: f32 [B][JQ][D] -> f16 [B][JQ][D] (straight) + f16 [B][D][JQ] (T) ----
__global__ void k_prep_q(const float* __restrict__ qg,
                         uint16_t* __restrict__ q16,
                         uint16_t* __restrict__ qT16) {
    __shared__ float tile[64][65];
    const int b = blockIdx.z, j0 = blockIdx.x * 64, d0 = blockIdx.y * 64;
    const int t = threadIdx.x;
    #pragma unroll
    for (int i = 0; i < 16; i++) {
        int e = t + 256 * i;
        int r = e >> 6, c = e & 63;
        float v = qg[((long)b * JQQ + j0 + r) * DDD + d0 + c];
        tile[r][c] = v;
        q16[((long)b * JQQ + j0 + r) * DDD + d0 + c] = f2h(v);
    }
    __syncthreads();
    #pragma unroll
    for (int i = 0; i < 16; i++) {
        int e = t + 256 * i;
        int c = e >> 6, r = e & 63;
        qT16[((long)b * DDD + d0 + c) * JQQ + j0 + r] = f2h(tile[r][c]);
    }
}

// ---- prep W: f32 [1024][256] (k,n) -> packed f16 frags WP[kt][nt][lane][8] ----
// element (k = kt*32 + g*8 + i, n = nt*16 + l15) at WP[((kt*16+nt)*64 + g*16+l15)*8 + i]
__global__ void k_prep_w(const float* __restrict__ Wr, const float* __restrict__ Wg,
                         uint16_t* __restrict__ WrP, uint16_t* __restrict__ WgP) {
    __shared__ _Float16 tile[32 * 264];
    const float* W = blockIdx.y ? Wg : Wr;
    uint16_t* WP = blockIdx.y ? WgP : WrP;
    const int kt = blockIdx.x, t = threadIdx.x;
    #pragma unroll
    for (int i = 0; i < 32; i++) {
        int e = t + 256 * i;
        int r = e >> 8, c = e & 255;
        tile[r * 264 + c] = (_Float16)W[(long)(kt * 32 + r) * 256 + c];
    }
    __syncthreads();
    #pragma unroll
    for (int ss = 0; ss < 4; ss++) {
        int slot = ss * 256 + t;             // 0..1023 = nt*64 + lane
        int nt = slot >> 6, lane = slot & 63;
        int gg = lane >> 4, l = lane & 15;
        f16x8 v;
        #pragma unroll
        for (int i = 0; i < 8; i++) v[i] = tile[(gg * 8 + i) * 264 + nt * 16 + l];
        *(f16x8*)(WP + ((long)(kt * 16 + nt) * 64 + lane) * 8) = v;
    }
}

// ---------------- fused attention v3: LDS-staged, x=32 per wave ----------------
// grid (JX/128, B), 256 thr, 4 waves x 32 x-rows. j staged 32 at a time.
// Logits mfma: D[j][x], x = lane&15 per xs-subtile. PV (swapped): D[d][x].
__global__ __launch_bounds__(256, 2) void k_attn(
    const float* __restrict__ cg,
    const uint16_t* __restrict__ q16,   // [B][JQ][D] f16
    const uint16_t* __restrict__ qT16,  // [B][D][JQ] f16
    const uint8_t* __restrict__ cm8,
    const uint8_t* __restrict__ qm8,
    uint16_t* __restrict__ qa16)        // [B][JX][D] f16
{
    __shared__ __align__(16) uint16_t q_lds[32 * 264];    // [j][d] pitch 264
    __shared__ __align__(16) uint16_t qT_lds[256 * 40];   // [d][j] pitch 40
    __shared__ __align__(16) uint16_t P_lds[4 * 32 * 40]; // per-wave [x(32)][j] pitch 40

    const int b = blockIdx.y;
    const int t = threadIdx.x;
    const int wave = t >> 6;
    const int lane = t & 63;
    const int l15 = lane & 15;
    const int g = lane >> 4;
    const int xw = blockIdx.x * 128 + wave * 32;

    // c fragments for two x-subtiles (B operand of logits), resident
    f16x8 cfrag[2][8];
    bool cvalid[2];
    float m_run[2], s_run[2];
    #pragma unroll
    for (int xs = 0; xs < 2; xs++) {
        const float* crow = cg + ((long)b * JXX + xw + xs * 16 + l15) * DDD;
        #pragma unroll
        for (int kb = 0; kb < 8; kb++) {
            float4 v0 = *(const float4*)(crow + kb * 32 + g * 8);
            float4 v1 = *(const float4*)(crow + kb * 32 + g * 8 + 4);
            f16x8 f;
            f[0] = (_Float16)v0.x; f[1] = (_Float16)v0.y; f[2] = (_Float16)v0.z; f[3] = (_Float16)v0.w;
            f[4] = (_Float16)v1.x; f[5] = (_Float16)v1.y; f[6] = (_Float16)v1.z; f[7] = (_Float16)v1.w;
            cfrag[xs][kb] = f;
        }
        cvalid[xs] = cm8[(long)b * JXX + xw + xs * 16 + l15] != 0;
        m_run[xs] = cvalid[xs] ? -1e30f : 0.0f;
        s_run[xs] = 0.0f;
    }
    const f32x4 fzero = {0.f, 0.f, 0.f, 0.f};
    f32x4 qa[16][2];   // qa[dt][xs][r] = q_aT[d=dt*16+g*4+r][x=xs*16+l15]
    #pragma unroll
    for (int i = 0; i < 16; i++) { qa[i][0] = fzero; qa[i][1] = fzero; }

    const uint16_t* qb  = q16  + (long)b * JQQ * DDD;
    const uint16_t* qTb = qT16 + (long)b * DDD * JQQ;
    const uint8_t*  qmb = qm8  + (long)b * JQQ;

    for (int jt = 0; jt < 16; jt++) {
        __syncthreads();
        // ---- stage q rows + qT (pure f16 b128 copies) ----
        #pragma unroll
        for (int i = 0; i < 4; i++) {
            int e = t + 256 * i;
            int row = e >> 5, c8 = e & 31;
            *(f16x8*)(q_lds + row * 264 + c8 * 8) =
                *(const f16x8*)(qb + (long)(jt * 32 + row) * DDD + c8 * 8);
        }
        #pragma unroll
        for (int i = 0; i < 4; i++) {
            int e = t + 256 * i;
            int d = e >> 2, gg = e & 3;
            *(f16x8*)(qT_lds + d * 40 + gg * 8) =
                *(const f16x8*)(qTb + (long)d * JQQ + jt * 32 + gg * 8);
        }
        __syncthreads();

        uint32_t qmw[2];
        qmw[0] = *(const uint32_t*)(qmb + jt * 32 + g * 4);
        qmw[1] = *(const uint32_t*)(qmb + jt * 32 + 16 + g * 4);

        // ---- logits: D[j][x], A-frag (q) reused across both xs ----
        f32x4 acc[2][2];   // [js][xs]
        acc[0][0] = fzero; acc[0][1] = fzero; acc[1][0] = fzero; acc[1][1] = fzero;
        #pragma unroll
        for (int js = 0; js < 2; js++) {
            #pragma unroll
            for (int kb = 0; kb < 8; kb++) {
                f16x8 qf = *(const f16x8*)(q_lds + (js * 16 + l15) * 264 + kb * 32 + g * 8);
                acc[js][0] = __builtin_amdgcn_mfma_f32_16x16x32_f16(qf, cfrag[0][kb], acc[js][0], 0, 0, 0);
                acc[js][1] = __builtin_amdgcn_mfma_f32_16x16x32_f16(qf, cfrag[1][kb], acc[js][1], 0, 0, 0);
            }
        }

        // ---- online softmax per xs (state per x = l15) ----
        f16x4 pv[2][2];   // [xs][js]
        float fsc[2];
        #pragma unroll
        for (int xs = 0; xs < 2; xs++) {
            float lmax = -1e30f;
            #pragma unroll
            for (int js = 0; js < 2; js++) {
                #pragma unroll
                for (int r = 0; r < 4; r++) {
                    bool qv = (qmw[js] >> (8 * r)) & 0xffu;
                    lmax = fmaxf(lmax, qv ? acc[js][xs][r] : -1e30f);
                }
            }
            lmax = fmaxf(lmax, __shfl_xor(lmax, 16));
            lmax = fmaxf(lmax, __shfl_xor(lmax, 32));
            float m_new = cvalid[xs] ? fmaxf(m_run[xs], lmax) : 0.0f;
            fsc[xs] = exp2f((m_run[xs] - m_new) * LOG2E);
            float psum = 0.0f;
            #pragma unroll
            for (int js = 0; js < 2; js++) {
                #pragma unroll
                for (int r = 0; r < 4; r++) {
                    bool qv = (qmw[js] >> (8 * r)) & 0xffu;
                    float p = qv ? exp2f((acc[js][xs][r] - m_new) * LOG2E) : 0.0f;
                    if (!cvalid[xs]) p = 1.0f;   // c-invalid row: uniform over ALL j
                    psum += p;
                    pv[xs][js][r] = (_Float16)p;
                }
            }
            s_run[xs] = s_run[xs] * fsc[xs] + psum;
            m_run[xs] = m_new;
        }
        if (!__all(fsc[0] == 1.0f && fsc[1] == 1.0f)) {
            #pragma unroll
            for (int dt = 0; dt < 16; dt++) {
                #pragma unroll
                for (int xs = 0; xs < 2; xs++) {
                    qa[dt][xs][0] *= fsc[xs]; qa[dt][xs][1] *= fsc[xs];
                    qa[dt][xs][2] *= fsc[xs]; qa[dt][xs][3] *= fsc[xs];
                }
            }
        }

        // ---- P re-layout via per-wave LDS (wave-private, no barrier) ----
        uint16_t* Pw0 = P_lds + wave * 1280;
        #pragma unroll
        for (int xs = 0; xs < 2; xs++) {
            *(f16x4*)(Pw0 + (xs * 16 + l15) * 40 + g * 4) = pv[xs][0];
            *(f16x4*)(Pw0 + (xs * 16 + l15) * 40 + 16 + g * 4) = pv[xs][1];
        }
        f16x8 pa[2];
        pa[0] = *(const f16x8*)(Pw0 + l15 * 40 + g * 8);
        pa[1] = *(const f16x8*)(Pw0 + (16 + l15) * 40 + g * 8);

        // ---- PV: A-frag (qT) reused across both xs ----
        #pragma unroll
        for (int dt = 0; dt < 16; dt++) {
            f16x8 bq = *(const f16x8*)(qT_lds + (dt * 16 + l15) * 40 + g * 8);
            qa[dt][0] = __builtin_amdgcn_mfma_f32_16x16x32_f16(bq, pa[0], qa[dt][0], 0, 0, 0);
            qa[dt][1] = __builtin_amdgcn_mfma_f32_16x16x32_f16(bq, pa[1], qa[dt][1], 0, 0, 0);
        }
    }

    // ---- finalize: divide by per-x sum (per-lane), store fp16 q_a ----
    #pragma unroll
    for (int xs = 0; xs < 2; xs++) {
        float s_tot = s_run[xs] + __shfl_xor(s_run[xs], 16);
        s_tot = s_tot + __shfl_xor(s_tot, 32);
        float inv = 1.0f / s_tot;
        uint16_t* outp = qa16 + ((long)b * JXX + xw + xs * 16 + l15) * DDD;
        #pragma unroll
        for (int dt = 0; dt < 16; dt++) {
            f16x4 v;
            v[0] = (_Float16)(qa[dt][xs][0] * inv);
            v[1] = (_Float16)(qa[dt][xs][1] * inv);
            v[2] = (_Float16)(qa[dt][xs][2] * inv);
            v[3] = (_Float16)(qa[dt][xs][3] * inv);
            *(f16x4*)(outp + dt * 16 + g * 4) = v;
        }
    }
}

// ---------------- fused SFU v3: m=128 block, wave = 32m x 128n, R+G ----------------
__global__ __launch_bounds__(256, 2) void k_sfu(
    const float* __restrict__ cg,
    const uint16_t* __restrict__ qa16,
    const uint16_t* __restrict__ WrP,   // packed frag layout
    const uint16_t* __restrict__ WgP,
    const float* __restrict__ Brb,
    const float* __restrict__ Bgb,
    float* __restrict__ outg)
{
    __shared__ __align__(16) uint16_t c_lds[128 * 72];
    __shared__ __align__(16) uint16_t qa_lds[128 * 72];

    const int t = threadIdx.x;
    const int wave = t >> 6;
    const int lane = t & 63;
    const int l15 = lane & 15, g = lane >> 4;
    const long m0 = (long)blockIdx.x * 128;
    const int n0 = blockIdx.y * 128, ny0 = blockIdx.y * 8;

    const f32x4 fzero = {0.f, 0.f, 0.f, 0.f};
    f32x4 accR[2][8], accG[2][8];
    #pragma unroll
    for (int a = 0; a < 2; a++)
        #pragma unroll
        for (int bq = 0; bq < 8; bq++) { accR[a][bq] = fzero; accG[a][bq] = fzero; }

    for (int dt = 0; dt < 4; dt++) {
        __syncthreads();
        // stage raw c (f32->f16) and qa (f16 copy) for this 64-d range, 128 rows
        #pragma unroll
        for (int i = 0; i < 4; i++) {
            int e = t + 256 * i;
            int row = e >> 3, c8 = e & 7;
            const float* p = cg + (m0 + row) * DDD + dt * 64 + c8 * 8;
            float4 v0 = *(const float4*)p;
            float4 v1 = *(const float4*)(p + 4);
            f16x8 f;
            f[0] = (_Float16)v0.x; f[1] = (_Float16)v0.y; f[2] = (_Float16)v0.z; f[3] = (_Float16)v0.w;
            f[4] = (_Float16)v1.x; f[5] = (_Float16)v1.y; f[6] = (_Float16)v1.z; f[7] = (_Float16)v1.w;
            *(f16x8*)(c_lds + row * 72 + c8 * 8) = f;
            *(f16x8*)(qa_lds + row * 72 + c8 * 8) =
                *(const f16x8*)(qa16 + (m0 + row) * DDD + dt * 64 + c8 * 8);
        }
        __syncthreads();
        #pragma unroll
        for (int kb = 0; kb < 2; kb++) {
            f16x8 af[4][2];
            #pragma unroll
            for (int mf = 0; mf < 2; mf++) {
                int row = wave * 32 + mf * 16 + l15;
                f16x8 cf = *(const f16x8*)(c_lds + row * 72 + kb * 32 + g * 8);
                f16x8 qf = *(const f16x8*)(qa_lds + row * 72 + kb * 32 + g * 8);
                af[0][mf] = cf;
                af[1][mf] = qf;
                af[2][mf] = cf * qf;   // packed f16
                af[3][mf] = cf - qf;
            }
            #pragma unroll
            for (int comp = 0; comp < 4; comp++) {
                int kt = comp * 8 + dt * 2 + kb;
                #pragma unroll
                for (int nt = 0; nt < 8; nt++) {
                    long slot = ((long)(kt * 16 + ny0 + nt) * 64 + lane) * 8;
                    f16x8 br = *(const f16x8*)(WrP + slot);
                    f16x8 bg = *(const f16x8*)(WgP + slot);
                    #pragma unroll
                    for (int mf = 0; mf < 2; mf++) {
                        accR[mf][nt] = __builtin_amdgcn_mfma_f32_16x16x32_f16(af[comp][mf], br, accR[mf][nt], 0, 0, 0);
                        accG[mf][nt] = __builtin_amdgcn_mfma_f32_16x16x32_f16(af[comp][mf], bg, accG[mf][nt], 0, 0, 0);
                    }
                }
            }
        }
    }
    // epilogue: D row = g*4 + r (m), col = l15 (n)
    #pragma unroll
    for (int nt = 0; nt < 8; nt++) {
        int n = n0 + nt * 16 + l15;
        float br = Brb[n], bg = Bgb[n];
        #pragma unroll
        for (int mf = 0; mf < 2; mf++) {
            long rowb = m0 + wave * 32 + mf * 16 + g * 4;
            #pragma unroll
            for (int r = 0; r < 4; r++) {
                float pr = accR[mf][nt][r] + br;
                float pg = accG[mf][nt][r] + bg;
                float x = fminf(fmaxf(pr, -30.f), 30.f);
                float e2 = __expf(2.f * x);
                float rr = (e2 - 1.f) / (e2 + 1.f);
                float gv = 1.0f / (1.0f + __expf(-pg));
                float cv = cg[(rowb + r) * DDD + n];
                outg[(rowb + r) * DDD + n] = gv * rr + (1.f - gv) * cv;
            }
        }
    }
}

extern "C" void kernel_launch(void* const* d_in, const int* in_sizes, int n_in,
                              void* d_out, int out_size, void* d_ws, size_t ws_size,
                              hipStream_t stream) {
    const float* c  = (const float*)d_in[0];
    const float* q  = (const float*)d_in[1];
    const float* Wr = (const float*)d_in[2];
    const float* Br = (const float*)d_in[3];
    const float* Wg = (const float*)d_in[4];
    const float* Bg = (const float*)d_in[5];
    const void* cmask = d_in[6];
    const void* qmask = d_in[7];

    char* ws = (char*)d_ws;
    uint16_t* q16   = (uint16_t*)(ws + 0);          //  4,194,304 B
    uint16_t* qT16  = (uint16_t*)(ws + 4194304);    //  4,194,304 B
    uint16_t* qa16  = (uint16_t*)(ws + 8388608);    // 33,554,432 B
    uint16_t* WrP   = (uint16_t*)(ws + 41943040);   //    524,288 B
    uint16_t* WgP   = (uint16_t*)(ws + 42467328);   //    524,288 B
    uint8_t*  cm8   = (uint8_t*)(ws + 42991616);    //     65,536 B
    uint8_t*  qm8   = (uint8_t*)(ws + 43057152);    //      8,192 B
    (void)in_sizes; (void)n_in; (void)out_size; (void)ws_size;

    k_mask<<<dim3((NB * JXX + 255) / 256), dim3(256), 0, stream>>>(cmask, qmask, cm8, qm8);
    k_prep_q<<<dim3(8, 4, NB), dim3(256), 0, stream>>>(q, q16, qT16);
    k_prep_w<<<dim3(32, 2), dim3(256), 0, stream>>>(Wr, Wg, WrP, WgP);
    k_attn<<<dim3(JXX / 128, NB), dim3(256), 0, stream>>>(c, q16, qT16, cm8, qm8, qa16);
    k_sfu<<<dim3((NB * JXX) / 128, 2), dim3(256), 0, stream>>>(
        c, qa16, WrP, WgP, Br, Bg, (float*)d_out);
}

// Round 6
// 195.800 us; speedup vs baseline: 1.8590x; 1.8561x over previous
//
#include <hip/hip_runtime.h>
#include <hip/hip_bf16.h>
#include <stdint.h>

#define NB 16
#define JXX 4096
#define JQQ 512
#define DDD 256
#define LOG2E 1.44269504f

typedef __attribute__((ext_vector_type(8))) _Float16 f16x8;
typedef __attribute__((ext_vector_type(4))) _Float16 f16x4;
typedef __attribute__((ext_vector_type(4))) float f32x4;

__device__ __forceinline__ uint16_t f2h(float f) {
    union { _Float16 h; uint16_t s; } u; u.h = (_Float16)f; return u.s;
}

__device__ __forceinline__ void gload_lds16(const void* g, void* l) {
    __builtin_amdgcn_global_load_lds(
        (const __attribute__((address_space(1))) void*)g,
        (__attribute__((address_space(3))) void*)l, 16, 0, 0);
}

// ---------------- mask canonicalization (dtype-detecting) ----------------
__global__ void k_mask(const void* cmask, const void* qmask,
                       uint8_t* cm8, uint8_t* qm8) {
    int i = blockIdx.x * 256 + threadIdx.x;
    uint32_t w0c = *(const uint32_t*)cmask;
    uint32_t w0q = *(const uint32_t*)qmask;
    int mc = (w0c == 1u) ? 1 : (w0c == 0x3f800000u ? 2 : 0);
    int mq = (w0q == 1u) ? 1 : (w0q == 0x3f800000u ? 2 : 0);
    if (i < NB * JXX) {
        uint8_t v;
        if (mc == 1)      v = ((const int*)cmask)[i] != 0;
        else if (mc == 2) v = ((const float*)cmask)[i] != 0.0f;
        else              v = ((const uint8_t*)cmask)[i] != 0;
        cm8[i] = v;
    }
    if (i < NB * JQQ) {
        uint8_t v;
        if (mq == 1)      v = ((const int*)qmask)[i] != 0;
        else if (mq == 2) v = ((const float*)qmask)[i] != 0.0f;
        else              v = ((const uint8_t*)qmask)[i] != 0;
        qm8[i] = v;
    }
}

// ---- prep q: f32 [B][JQ][D] -> f16 [B][JQ][D] (straight) + f16 [B][D][JQ] (T) ----
__global__ void k_prep_q(const float* __restrict__ qg,
                         uint16_t* __restrict__ q16,
                         uint16_t* __restrict__ qT16) {
    __shared__ float tile[64][65];
    const int b = blockIdx.z, j0 = blockIdx.x * 64, d0 = blockIdx.y * 64;
    const int t = threadIdx.x;
    #pragma unroll
    for (int i = 0; i < 16; i++) {
        int e = t + 256 * i;
        int r = e >> 6, c = e & 63;
        float v = qg[((long)b * JQQ + j0 + r) * DDD + d0 + c];
        tile[r][c] = v;
        q16[((long)b * JQQ + j0 + r) * DDD + d0 + c] = f2h(v);
    }
    __syncthreads();
    #pragma unroll
    for (int i = 0; i < 16; i++) {
        int e = t + 256 * i;
        int c = e >> 6, r = e & 63;
        qT16[((long)b * DDD + d0 + c) * JQQ + j0 + r] = f2h(tile[r][c]);
    }
}

// ---- prep W: f32 [1024][256] (k,n) -> packed f16 frags WP[kt][nt][lane][8] ----
// element (k = kt*32 + g*8 + i, n = nt*16 + l15) at WP[((kt*16+nt)*64 + g*16+l15)*8 + i]
__global__ void k_prep_w(const float* __restrict__ Wr, const float* __restrict__ Wg,
                         uint16_t* __restrict__ WrP, uint16_t* __restrict__ WgP) {
    __shared__ _Float16 tile[32 * 264];
    const float* W = blockIdx.y ? Wg : Wr;
    uint16_t* WP = blockIdx.y ? WgP : WrP;
    const int kt = blockIdx.x, t = threadIdx.x;
    #pragma unroll
    for (int i = 0; i < 32; i++) {
        int e = t + 256 * i;
        int r = e >> 8, c = e & 255;
        tile[r * 264 + c] = (_Float16)W[(long)(kt * 32 + r) * 256 + c];
    }
    __syncthreads();
    #pragma unroll
    for (int ss = 0; ss < 4; ss++) {
        int slot = ss * 256 + t;             // 0..1023 = nt*64 + lane
        int nt = slot >> 6, lane = slot & 63;
        int gg = lane >> 4, l = lane & 15;
        f16x8 v;
        #pragma unroll
        for (int i = 0; i < 8; i++) v[i] = tile[(gg * 8 + i) * 264 + nt * 16 + l];
        *(f16x8*)(WP + ((long)(kt * 16 + nt) * 64 + lane) * 8) = v;
    }
}

// ---------------- fused attention v3: LDS-staged, x=32 per wave (unchanged) ----------------
__global__ __launch_bounds__(256, 2) void k_attn(
    const float* __restrict__ cg,
    const uint16_t* __restrict__ q16,   // [B][JQ][D] f16
    const uint16_t* __restrict__ qT16,  // [B][D][JQ] f16
    const uint8_t* __restrict__ cm8,
    const uint8_t* __restrict__ qm8,
    uint16_t* __restrict__ qa16)        // [B][JX][D] f16
{
    __shared__ __align__(16) uint16_t q_lds[32 * 264];    // [j][d] pitch 264
    __shared__ __align__(16) uint16_t qT_lds[256 * 40];   // [d][j] pitch 40
    __shared__ __align__(16) uint16_t P_lds[4 * 32 * 40]; // per-wave [x(32)][j] pitch 40

    const int b = blockIdx.y;
    const int t = threadIdx.x;
    const int wave = t >> 6;
    const int lane = t & 63;
    const int l15 = lane & 15;
    const int g = lane >> 4;
    const int xw = blockIdx.x * 128 + wave * 32;

    f16x8 cfrag[2][8];
    bool cvalid[2];
    float m_run[2], s_run[2];
    #pragma unroll
    for (int xs = 0; xs < 2; xs++) {
        const float* crow = cg + ((long)b * JXX + xw + xs * 16 + l15) * DDD;
        #pragma unroll
        for (int kb = 0; kb < 8; kb++) {
            float4 v0 = *(const float4*)(crow + kb * 32 + g * 8);
            float4 v1 = *(const float4*)(crow + kb * 32 + g * 8 + 4);
            f16x8 f;
            f[0] = (_Float16)v0.x; f[1] = (_Float16)v0.y; f[2] = (_Float16)v0.z; f[3] = (_Float16)v0.w;
            f[4] = (_Float16)v1.x; f[5] = (_Float16)v1.y; f[6] = (_Float16)v1.z; f[7] = (_Float16)v1.w;
            cfrag[xs][kb] = f;
        }
        cvalid[xs] = cm8[(long)b * JXX + xw + xs * 16 + l15] != 0;
        m_run[xs] = cvalid[xs] ? -1e30f : 0.0f;
        s_run[xs] = 0.0f;
    }
    const f32x4 fzero = {0.f, 0.f, 0.f, 0.f};
    f32x4 qa[16][2];
    #pragma unroll
    for (int i = 0; i < 16; i++) { qa[i][0] = fzero; qa[i][1] = fzero; }

    const uint16_t* qb  = q16  + (long)b * JQQ * DDD;
    const uint16_t* qTb = qT16 + (long)b * DDD * JQQ;
    const uint8_t*  qmb = qm8  + (long)b * JQQ;

    for (int jt = 0; jt < 16; jt++) {
        __syncthreads();
        #pragma unroll
        for (int i = 0; i < 4; i++) {
            int e = t + 256 * i;
            int row = e >> 5, c8 = e & 31;
            *(f16x8*)(q_lds + row * 264 + c8 * 8) =
                *(const f16x8*)(qb + (long)(jt * 32 + row) * DDD + c8 * 8);
        }
        #pragma unroll
        for (int i = 0; i < 4; i++) {
            int e = t + 256 * i;
            int d = e >> 2, gg = e & 3;
            *(f16x8*)(qT_lds + d * 40 + gg * 8) =
                *(const f16x8*)(qTb + (long)d * JQQ + jt * 32 + gg * 8);
        }
        __syncthreads();

        uint32_t qmw[2];
        qmw[0] = *(const uint32_t*)(qmb + jt * 32 + g * 4);
        qmw[1] = *(const uint32_t*)(qmb + jt * 32 + 16 + g * 4);

        f32x4 acc[2][2];
        acc[0][0] = fzero; acc[0][1] = fzero; acc[1][0] = fzero; acc[1][1] = fzero;
        #pragma unroll
        for (int js = 0; js < 2; js++) {
            #pragma unroll
            for (int kb = 0; kb < 8; kb++) {
                f16x8 qf = *(const f16x8*)(q_lds + (js * 16 + l15) * 264 + kb * 32 + g * 8);
                acc[js][0] = __builtin_amdgcn_mfma_f32_16x16x32_f16(qf, cfrag[0][kb], acc[js][0], 0, 0, 0);
                acc[js][1] = __builtin_amdgcn_mfma_f32_16x16x32_f16(qf, cfrag[1][kb], acc[js][1], 0, 0, 0);
            }
        }

        f16x4 pv[2][2];
        float fsc[2];
        #pragma unroll
        for (int xs = 0; xs < 2; xs++) {
            float lmax = -1e30f;
            #pragma unroll
            for (int js = 0; js < 2; js++) {
                #pragma unroll
                for (int r = 0; r < 4; r++) {
                    bool qv = (qmw[js] >> (8 * r)) & 0xffu;
                    lmax = fmaxf(lmax, qv ? acc[js][xs][r] : -1e30f);
                }
            }
            lmax = fmaxf(lmax, __shfl_xor(lmax, 16));
            lmax = fmaxf(lmax, __shfl_xor(lmax, 32));
            float m_new = cvalid[xs] ? fmaxf(m_run[xs], lmax) : 0.0f;
            fsc[xs] = exp2f((m_run[xs] - m_new) * LOG2E);
            float psum = 0.0f;
            #pragma unroll
            for (int js = 0; js < 2; js++) {
                #pragma unroll
                for (int r = 0; r < 4; r++) {
                    bool qv = (qmw[js] >> (8 * r)) & 0xffu;
                    float p = qv ? exp2f((acc[js][xs][r] - m_new) * LOG2E) : 0.0f;
                    if (!cvalid[xs]) p = 1.0f;
                    psum += p;
                    pv[xs][js][r] = (_Float16)p;
                }
            }
            s_run[xs] = s_run[xs] * fsc[xs] + psum;
            m_run[xs] = m_new;
        }
        if (!__all(fsc[0] == 1.0f && fsc[1] == 1.0f)) {
            #pragma unroll
            for (int dt = 0; dt < 16; dt++) {
                #pragma unroll
                for (int xs = 0; xs < 2; xs++) {
                    qa[dt][xs][0] *= fsc[xs]; qa[dt][xs][1] *= fsc[xs];
                    qa[dt][xs][2] *= fsc[xs]; qa[dt][xs][3] *= fsc[xs];
                }
            }
        }

        uint16_t* Pw0 = P_lds + wave * 1280;
        #pragma unroll
        for (int xs = 0; xs < 2; xs++) {
            *(f16x4*)(Pw0 + (xs * 16 + l15) * 40 + g * 4) = pv[xs][0];
            *(f16x4*)(Pw0 + (xs * 16 + l15) * 40 + 16 + g * 4) = pv[xs][1];
        }
        f16x8 pa[2];
        pa[0] = *(const f16x8*)(Pw0 + l15 * 40 + g * 8);
        pa[1] = *(const f16x8*)(Pw0 + (16 + l15) * 40 + g * 8);

        #pragma unroll
        for (int dt = 0; dt < 16; dt++) {
            f16x8 bq = *(const f16x8*)(qT_lds + (dt * 16 + l15) * 40 + g * 8);
            qa[dt][0] = __builtin_amdgcn_mfma_f32_16x16x32_f16(bq, pa[0], qa[dt][0], 0, 0, 0);
            qa[dt][1] = __builtin_amdgcn_mfma_f32_16x16x32_f16(bq, pa[1], qa[dt][1], 0, 0, 0);
        }
    }

    #pragma unroll
    for (int xs = 0; xs < 2; xs++) {
        float s_tot = s_run[xs] + __shfl_xor(s_run[xs], 16);
        s_tot = s_tot + __shfl_xor(s_tot, 32);
        float inv = 1.0f / s_tot;
        uint16_t* outp = qa16 + ((long)b * JXX + xw + xs * 16 + l15) * DDD;
        #pragma unroll
        for (int dt = 0; dt < 16; dt++) {
            f16x4 v;
            v[0] = (_Float16)(qa[dt][xs][0] * inv);
            v[1] = (_Float16)(qa[dt][xs][1] * inv);
            v[2] = (_Float16)(qa[dt][xs][2] * inv);
            v[3] = (_Float16)(qa[dt][xs][3] * inv);
            *(f16x4*)(outp + dt * 16 + g * 4) = v;
        }
    }
}

// ---------------- fused SFU v4: m=64 block, W via LDS double-buffer pipeline ----------------
// grid (M/64, 2), 256 thr, wave = 32m x 64n. 32 steps; per step: stage next 16 KB
// (R+G frags for 8 n-slots) via global_load_lds, vmcnt(4), raw barriers, 16 MFMA.
__global__ __launch_bounds__(256, 3) void k_sfu(
    const float* __restrict__ cg,
    const uint16_t* __restrict__ qa16,
    const uint16_t* __restrict__ WrP,   // packed frag layout
    const uint16_t* __restrict__ WgP,
    const float* __restrict__ Brb,
    const float* __restrict__ Bgb,
    float* __restrict__ outg)
{
    __shared__ __align__(16) uint16_t c_lds[64 * 72];
    __shared__ __align__(16) uint16_t qa_lds[64 * 72];
    __shared__ __align__(16) uint16_t wbuf[2][8192];    // 2 x 16 KB

    const int t = threadIdx.x;
    const int wave = t >> 6;
    const int lane = t & 63;
    const int l15 = lane & 15, g = lane >> 4;
    const int mw = wave & 1, nw = wave >> 1;
    const long m0 = (long)blockIdx.x * 64;
    const int n0 = blockIdx.y * 128, ny0 = blockIdx.y * 8;

    const f32x4 fzero = {0.f, 0.f, 0.f, 0.f};
    f32x4 accR[2][4], accG[2][4];
    #pragma unroll
    for (int a = 0; a < 2; a++)
        #pragma unroll
        for (int bq = 0; bq < 4; bq++) { accR[a][bq] = fzero; accG[a][bq] = fzero; }

    // stage slots: s = i*4 + wave; s<8 -> R slot ny0+s; s>=8 -> G slot ny0+s-8.
    // LDS dest (wave-uniform): buf + i*2048 + wave*512 u16; HW adds lane*16B.
    #define STAGE_W(bufp, kt)                                                     \
        {                                                                         \
            _Pragma("unroll")                                                     \
            for (int i = 0; i < 4; i++) {                                         \
                int s = i * 4 + wave;                                             \
                const uint16_t* src = (s < 8)                                     \
                    ? WrP + ((long)((kt) * 16 + ny0 + s) * 64 + lane) * 8         \
                    : WgP + ((long)((kt) * 16 + ny0 + s - 8) * 64 + lane) * 8;    \
                gload_lds16(src, (bufp) + i * 2048 + wave * 512);                 \
            }                                                                     \
        }

    int cur = 0;
    STAGE_W(&wbuf[0][0], 0);   // prologue: (dt0,kb0,comp0) -> kt = 0

    #pragma unroll
    for (int dt = 0; dt < 4; dt++) {
        __syncthreads();
        // stage c (f32->f16) and qa (f16 copy) for this 64-d range
        #pragma unroll
        for (int i = 0; i < 2; i++) {
            int e = t + 256 * i;
            int row = e >> 3, c8 = e & 7;
            const float* p = cg + (m0 + row) * DDD + dt * 64 + c8 * 8;
            float4 v0 = *(const float4*)p;
            float4 v1 = *(const float4*)(p + 4);
            f16x8 f;
            f[0] = (_Float16)v0.x; f[1] = (_Float16)v0.y; f[2] = (_Float16)v0.z; f[3] = (_Float16)v0.w;
            f[4] = (_Float16)v1.x; f[5] = (_Float16)v1.y; f[6] = (_Float16)v1.z; f[7] = (_Float16)v1.w;
            *(f16x8*)(c_lds + row * 72 + c8 * 8) = f;
            *(f16x8*)(qa_lds + row * 72 + c8 * 8) =
                *(const f16x8*)(qa16 + (m0 + row) * DDD + dt * 64 + c8 * 8);
        }
        __syncthreads();
        #pragma unroll
        for (int kb = 0; kb < 2; kb++) {
            f16x8 af[4][2];
            #pragma unroll
            for (int mf = 0; mf < 2; mf++) {
                int row = mw * 32 + mf * 16 + l15;
                f16x8 cf = *(const f16x8*)(c_lds + row * 72 + kb * 32 + g * 8);
                f16x8 qf = *(const f16x8*)(qa_lds + row * 72 + kb * 32 + g * 8);
                af[0][mf] = cf;
                af[1][mf] = qf;
                af[2][mf] = cf * qf;
                af[3][mf] = cf - qf;
            }
            #pragma unroll
            for (int comp = 0; comp < 4; comp++) {
                const int step = (dt * 2 + kb) * 4 + comp;
                if (step < 31) {
                    // next step indices (comp-major within (dt,kb))
                    const int ns = step + 1;
                    const int ndt = ns >> 3, nkb = (ns >> 2) & 1, ncomp = ns & 3;
                    const int nkt = ncomp * 8 + ndt * 2 + nkb;
                    STAGE_W(&wbuf[cur ^ 1][0], nkt);
                    asm volatile("s_waitcnt vmcnt(4)" ::: "memory");
                } else {
                    asm volatile("s_waitcnt vmcnt(0)" ::: "memory");
                }
                __builtin_amdgcn_s_barrier();
                __builtin_amdgcn_sched_barrier(0);
                const uint16_t* Wb = &wbuf[cur][0];
                #pragma unroll
                for (int nt = 0; nt < 4; nt++) {
                    f16x8 br = *(const f16x8*)(Wb + (nw * 4 + nt) * 512 + lane * 8);
                    f16x8 bg = *(const f16x8*)(Wb + 4096 + (nw * 4 + nt) * 512 + lane * 8);
                    accR[0][nt] = __builtin_amdgcn_mfma_f32_16x16x32_f16(af[comp][0], br, accR[0][nt], 0, 0, 0);
                    accR[1][nt] = __builtin_amdgcn_mfma_f32_16x16x32_f16(af[comp][1], br, accR[1][nt], 0, 0, 0);
                    accG[0][nt] = __builtin_amdgcn_mfma_f32_16x16x32_f16(af[comp][0], bg, accG[0][nt], 0, 0, 0);
                    accG[1][nt] = __builtin_amdgcn_mfma_f32_16x16x32_f16(af[comp][1], bg, accG[1][nt], 0, 0, 0);
                }
                __builtin_amdgcn_sched_barrier(0);
                __builtin_amdgcn_s_barrier();
                cur ^= 1;
            }
        }
    }
    #undef STAGE_W

    // epilogue: D row = g*4 + r (m), col = l15 (n)
    #pragma unroll
    for (int nt = 0; nt < 4; nt++) {
        int n = n0 + nw * 64 + nt * 16 + l15;
        float br = Brb[n], bg = Bgb[n];
        #pragma unroll
        for (int mf = 0; mf < 2; mf++) {
            long rowb = m0 + mw * 32 + mf * 16 + g * 4;
            #pragma unroll
            for (int r = 0; r < 4; r++) {
                float pr = accR[mf][nt][r] + br;
                float pg = accG[mf][nt][r] + bg;
                float x = fminf(fmaxf(pr, -30.f), 30.f);
                float e2 = __expf(2.f * x);
                float rr = (e2 - 1.f) / (e2 + 1.f);
                float gv = 1.0f / (1.0f + __expf(-pg));
                float cv = cg[(rowb + r) * DDD + n];
                outg[(rowb + r) * DDD + n] = gv * rr + (1.f - gv) * cv;
            }
        }
    }
}

extern "C" void kernel_launch(void* const* d_in, const int* in_sizes, int n_in,
                              void* d_out, int out_size, void* d_ws, size_t ws_size,
                              hipStream_t stream) {
    const float* c  = (const float*)d_in[0];
    const float* q  = (const float*)d_in[1];
    const float* Wr = (const float*)d_in[2];
    const float* Br = (const float*)d_in[3];
    const float* Wg = (const float*)d_in[4];
    const float* Bg = (const float*)d_in[5];
    const void* cmask = d_in[6];
    const void* qmask = d_in[7];

    char* ws = (char*)d_ws;
    uint16_t* q16   = (uint16_t*)(ws + 0);          //  4,194,304 B
    uint16_t* qT16  = (uint16_t*)(ws + 4194304);    //  4,194,304 B
    uint16_t* qa16  = (uint16_t*)(ws + 8388608);    // 33,554,432 B
    uint16_t* WrP   = (uint16_t*)(ws + 41943040);   //    524,288 B
    uint16_t* WgP   = (uint16_t*)(ws + 42467328);   //    524,288 B
    uint8_t*  cm8   = (uint8_t*)(ws + 42991616);    //     65,536 B
    uint8_t*  qm8   = (uint8_t*)(ws + 43057152);    //      8,192 B
    (void)in_sizes; (void)n_in; (void)out_size; (void)ws_size;

    k_mask<<<dim3((NB * JXX + 255) / 256), dim3(256), 0, stream>>>(cmask, qmask, cm8, qm8);
    k_prep_q<<<dim3(8, 4, NB), dim3(256), 0, stream>>>(q, q16, qT16);
    k_prep_w<<<dim3(32, 2), dim3(256), 0, stream>>>(Wr, Wg, WrP, WgP);
    k_attn<<<dim3(JXX / 128, NB), dim3(256), 0, stream>>>(c, q16, qT16, cm8, qm8, qa16);
    k_sfu<<<dim3((NB * JXX) / 64, 2), dim3(256), 0, stream>>>(
        c, qa16, WrP, WgP, Br, Bg, (float*)d_out);
}

// Round 8
// 168.755 us; speedup vs baseline: 2.1569x; 1.1603x over previous
//
#include <hip/hip_runtime.h>
#include <hip/hip_bf16.h>
#include <stdint.h>

#define NB 16
#define JXX 4096
#define JQQ 512
#define DDD 256
#define LOG2E 1.44269504f

typedef __attribute__((ext_vector_type(8))) _Float16 f16x8;
typedef __attribute__((ext_vector_type(4))) _Float16 f16x4;
typedef __attribute__((ext_vector_type(4))) float f32x4;

__device__ __forceinline__ uint16_t f2h(float f) {
    union { _Float16 h; uint16_t s; } u; u.h = (_Float16)f; return u.s;
}

__device__ __forceinline__ void gload_lds16(const void* g, void* l) {
    __builtin_amdgcn_global_load_lds(
        (const __attribute__((address_space(1))) void*)g,
        (__attribute__((address_space(3))) void*)l, 16, 0, 0);
}

// ---------------- mask canonicalization (dtype-detecting) ----------------
__global__ void k_mask(const void* cmask, const void* qmask,
                       uint8_t* cm8, uint8_t* qm8) {
    int i = blockIdx.x * 256 + threadIdx.x;
    uint32_t w0c = *(const uint32_t*)cmask;
    uint32_t w0q = *(const uint32_t*)qmask;
    int mc = (w0c == 1u) ? 1 : (w0c == 0x3f800000u ? 2 : 0);
    int mq = (w0q == 1u) ? 1 : (w0q == 0x3f800000u ? 2 : 0);
    if (i < NB * JXX) {
        uint8_t v;
        if (mc == 1)      v = ((const int*)cmask)[i] != 0;
        else if (mc == 2) v = ((const float*)cmask)[i] != 0.0f;
        else              v = ((const uint8_t*)cmask)[i] != 0;
        cm8[i] = v;
    }
    if (i < NB * JQQ) {
        uint8_t v;
        if (mq == 1)      v = ((const int*)qmask)[i] != 0;
        else if (mq == 2) v = ((const float*)qmask)[i] != 0.0f;
        else              v = ((const uint8_t*)qmask)[i] != 0;
        qm8[i] = v;
    }
}

// ---- prep q: f32 [B][JQ][D] -> pre-swizzled 16KB LDS-image tiles ----
// qS[b][jt]: [row=j&31][d] u16, byte ^= (row&7)<<4   (16B-granular)
// qTS[b][jt]: [d][j&31] u16,  byte ^= ((d>>1)&3)<<4
__global__ void k_prep_q(const float* __restrict__ qg,
                         uint16_t* __restrict__ qS,
                         uint16_t* __restrict__ qTS) {
    __shared__ float tile[64][65];
    const int b = blockIdx.z, j0 = blockIdx.x * 64, d0 = blockIdx.y * 64;
    const int t = threadIdx.x;
    #pragma unroll
    for (int i = 0; i < 16; i++) {
        int e = t + 256 * i;
        int r = e >> 6, c = e & 63;
        tile[r][c] = qg[((long)b * JQQ + j0 + r) * DDD + d0 + c];
    }
    __syncthreads();
    // qS: chunks (r=0..63, c8=0..7) -> 8 u16 at d = d0 + c8*8
    #pragma unroll
    for (int i = 0; i < 2; i++) {
        int e = t + 256 * i;
        int r = e >> 3, c8 = e & 7;
        f16x8 v;
        #pragma unroll
        for (int k = 0; k < 8; k++) v[k] = (_Float16)tile[r][c8 * 8 + k];
        int jt = (j0 >> 5) + (r >> 5);
        int row = r & 31;
        int d8 = (d0 >> 3) + c8;
        int byt = ((row * 512 + d8 * 16) ^ ((row & 7) << 4));
        *(f16x8*)(qS + ((long)(b * 16 + jt)) * 8192 + (byt >> 1)) = v;
    }
    // qTS: chunks (dd=0..63, j8=0..7) -> 8 u16 at j = j0 + j8*8
    #pragma unroll
    for (int i = 0; i < 2; i++) {
        int e = t + 256 * i;
        int dd = e >> 3, j8 = e & 7;
        f16x8 v;
        #pragma unroll
        for (int k = 0; k < 8; k++) v[k] = (_Float16)tile[j8 * 8 + k][dd];
        int jt = (j0 >> 5) + (j8 >> 2);
        int d = d0 + dd;
        int byt = ((d * 64 + (j8 & 3) * 16) ^ (((d >> 1) & 3) << 4));
        *(f16x8*)(qTS + ((long)(b * 16 + jt)) * 8192 + (byt >> 1)) = v;
    }
}

// ---- prep W: f32 [1024][256] (k,n) -> packed f16 frags WP[kt][nt][lane][8] ----
__global__ void k_prep_w(const float* __restrict__ Wr, const float* __restrict__ Wg,
                         uint16_t* __restrict__ WrP, uint16_t* __restrict__ WgP) {
    __shared__ _Float16 tile[32 * 264];
    const float* W = blockIdx.y ? Wg : Wr;
    uint16_t* WP = blockIdx.y ? WgP : WrP;
    const int kt = blockIdx.x, t = threadIdx.x;
    #pragma unroll
    for (int i = 0; i < 32; i++) {
        int e = t + 256 * i;
        int r = e >> 8, c = e & 255;
        tile[r * 264 + c] = (_Float16)W[(long)(kt * 32 + r) * 256 + c];
    }
    __syncthreads();
    #pragma unroll
    for (int ss = 0; ss < 4; ss++) {
        int slot = ss * 256 + t;
        int nt = slot >> 6, lane = slot & 63;
        int gg = lane >> 4, l = lane & 15;
        f16x8 v;
        #pragma unroll
        for (int i = 0; i < 8; i++) v[i] = tile[(gg * 8 + i) * 264 + nt * 16 + l];
        *(f16x8*)(WP + ((long)(kt * 16 + nt) * 64 + lane) * 8) = v;
    }
}

// ---------------- fused attention v4b: double-buffered gload_lds pipeline ----------------
// grid (JX/128, B), 256 thr, 4 waves x 32 x-rows. Per jt: stage next 32KB tile pair,
// vmcnt(8), raw barriers. Swizzled conflict-free reads.
// NOTE: swizzled ADDRESS uses (kb^kbit); the DATA it returns is chunk kb -> pair cfrag[kb].
__global__ __launch_bounds__(256, 2) void k_attn(
    const float* __restrict__ cg,
    const uint16_t* __restrict__ qS,    // [B][16][8192] swizzled [j][d] tiles
    const uint16_t* __restrict__ qTS,   // [B][16][8192] swizzled [d][j] tiles
    const uint8_t* __restrict__ cm8,
    const uint8_t* __restrict__ qm8,
    uint16_t* __restrict__ qa16)        // [B][JX][D] f16
{
    __shared__ __align__(16) uint16_t qbuf[2][8192];
    __shared__ __align__(16) uint16_t qTbuf[2][8192];
    __shared__ __align__(16) uint16_t P_lds[4 * 32 * 40]; // per-wave [x(32)][j] pitch 40
    __shared__ __align__(16) uint32_t qm_lds[128];

    const int b = blockIdx.y;
    const int t = threadIdx.x;
    const int wave = t >> 6;
    const int lane = t & 63;
    const int l15 = lane & 15;
    const int g = lane >> 4;
    const int xw = blockIdx.x * 128 + wave * 32;

    // masks -> LDS (before staging: keeps loop vmem = staging only)
    if (t < 128) {
        uint32_t m = ((const uint32_t*)(qm8 + (long)b * JQQ))[t];
        qm_lds[t] = m;
    }

    // c fragments for two x-subtiles (B operand of logits), resident
    f16x8 cfrag[2][8];
    bool cvalid[2];
    float m_run[2], s_run[2];
    #pragma unroll
    for (int xs = 0; xs < 2; xs++) {
        const float* crow = cg + ((long)b * JXX + xw + xs * 16 + l15) * DDD;
        #pragma unroll
        for (int kb = 0; kb < 8; kb++) {
            float4 v0 = *(const float4*)(crow + kb * 32 + g * 8);
            float4 v1 = *(const float4*)(crow + kb * 32 + g * 8 + 4);
            f16x8 f;
            f[0] = (_Float16)v0.x; f[1] = (_Float16)v0.y; f[2] = (_Float16)v0.z; f[3] = (_Float16)v0.w;
            f[4] = (_Float16)v1.x; f[5] = (_Float16)v1.y; f[6] = (_Float16)v1.z; f[7] = (_Float16)v1.w;
            cfrag[xs][kb] = f;
        }
        cvalid[xs] = cm8[(long)b * JXX + xw + xs * 16 + l15] != 0;
        m_run[xs] = cvalid[xs] ? -1e30f : 0.0f;
        s_run[xs] = 0.0f;
    }
    const f32x4 fzero = {0.f, 0.f, 0.f, 0.f};
    f32x4 qa[16][2];
    #pragma unroll
    for (int i = 0; i < 16; i++) { qa[i][0] = fzero; qa[i][1] = fzero; }

    const uint16_t* qSb  = qS  + (long)(b * 16) * 8192;
    const uint16_t* qTSb = qTS + (long)(b * 16) * 8192;

    // per-lane swizzled read bases (u16 units)
    const int kbit = (l15 >> 2) & 1;                               // logits kb-XOR bit
    const int qbase = l15 * 256 + (((g * 16) ^ ((l15 & 3) << 4)) >> 1);
    const int qTbase = l15 * 32 + ((g ^ ((l15 >> 1) & 3)) * 8);

    #define STAGE_ATTN(bsel, tile)                                              \
        {                                                                       \
            const uint16_t* s1 = qSb + (long)(tile) * 8192;                     \
            const uint16_t* s2 = qTSb + (long)(tile) * 8192;                    \
            _Pragma("unroll")                                                   \
            for (int i = 0; i < 4; i++)                                         \
                gload_lds16(s1 + i * 2048 + t * 8,                              \
                            &qbuf[bsel][i * 2048 + wave * 512]);                \
            _Pragma("unroll")                                                   \
            for (int i = 0; i < 4; i++)                                         \
                gload_lds16(s2 + i * 2048 + t * 8,                              \
                            &qTbuf[bsel][i * 2048 + wave * 512]);               \
        }

    STAGE_ATTN(0, 0);   // prologue
    asm volatile("s_waitcnt lgkmcnt(0)" ::: "memory");
    __builtin_amdgcn_s_barrier();   // qm_lds visible (doesn't drain vmcnt)

    int cur = 0;
    for (int jt = 0; jt < 16; jt++) {
        if (jt < 15) {
            STAGE_ATTN(cur ^ 1, jt + 1);
            asm volatile("s_waitcnt vmcnt(8)" ::: "memory");
        } else {
            asm volatile("s_waitcnt vmcnt(0)" ::: "memory");
        }
        __builtin_amdgcn_s_barrier();
        __builtin_amdgcn_sched_barrier(0);

        const uint16_t* qb_l  = &qbuf[cur][0];
        const uint16_t* qTb_l = &qTbuf[cur][0];

        uint32_t qmw[2];
        qmw[0] = qm_lds[jt * 8 + g];
        qmw[1] = qm_lds[jt * 8 + 4 + g];

        // ---- logits: D[j][x], swizzled conflict-free reads ----
        // address chunk (kb^kbit) returns DATA chunk kb  ->  pair with cfrag[kb]
        f32x4 acc[2][2];   // [js][xs]
        acc[0][0] = fzero; acc[0][1] = fzero; acc[1][0] = fzero; acc[1][1] = fzero;
        #pragma unroll
        for (int js = 0; js < 2; js++) {
            #pragma unroll
            for (int kb = 0; kb < 8; kb++) {
                f16x8 qf = *(const f16x8*)(qb_l + js * 4096 + qbase + ((kb ^ kbit) << 5));
                acc[js][0] = __builtin_amdgcn_mfma_f32_16x16x32_f16(qf, cfrag[0][kb], acc[js][0], 0, 0, 0);
                acc[js][1] = __builtin_amdgcn_mfma_f32_16x16x32_f16(qf, cfrag[1][kb], acc[js][1], 0, 0, 0);
            }
        }

        // ---- online softmax per xs (state per x = l15) ----
        f16x4 pv[2][2];
        float fsc[2];
        #pragma unroll
        for (int xs = 0; xs < 2; xs++) {
            float lmax = -1e30f;
            #pragma unroll
            for (int js = 0; js < 2; js++) {
                #pragma unroll
                for (int r = 0; r < 4; r++) {
                    bool qv = (qmw[js] >> (8 * r)) & 0xffu;
                    lmax = fmaxf(lmax, qv ? acc[js][xs][r] : -1e30f);
                }
            }
            lmax = fmaxf(lmax, __shfl_xor(lmax, 16));
            lmax = fmaxf(lmax, __shfl_xor(lmax, 32));
            float m_new = cvalid[xs] ? fmaxf(m_run[xs], lmax) : 0.0f;
            fsc[xs] = exp2f((m_run[xs] - m_new) * LOG2E);
            float psum = 0.0f;
            #pragma unroll
            for (int js = 0; js < 2; js++) {
                #pragma unroll
                for (int r = 0; r < 4; r++) {
                    bool qv = (qmw[js] >> (8 * r)) & 0xffu;
                    float p = qv ? exp2f((acc[js][xs][r] - m_new) * LOG2E) : 0.0f;
                    if (!cvalid[xs]) p = 1.0f;   // c-invalid row: uniform over ALL j
                    psum += p;
                    pv[xs][js][r] = (_Float16)p;
                }
            }
            s_run[xs] = s_run[xs] * fsc[xs] + psum;
            m_run[xs] = m_new;
        }
        if (!__all(fsc[0] == 1.0f && fsc[1] == 1.0f)) {
            #pragma unroll
            for (int dt = 0; dt < 16; dt++) {
                #pragma unroll
                for (int xs = 0; xs < 2; xs++) {
                    qa[dt][xs][0] *= fsc[xs]; qa[dt][xs][1] *= fsc[xs];
                    qa[dt][xs][2] *= fsc[xs]; qa[dt][xs][3] *= fsc[xs];
                }
            }
        }

        // ---- P re-layout via per-wave LDS (wave-private, no barrier) ----
        uint16_t* Pw0 = P_lds + wave * 1280;
        #pragma unroll
        for (int xs = 0; xs < 2; xs++) {
            *(f16x4*)(Pw0 + (xs * 16 + l15) * 40 + g * 4) = pv[xs][0];
            *(f16x4*)(Pw0 + (xs * 16 + l15) * 40 + 16 + g * 4) = pv[xs][1];
        }
        f16x8 pa[2];
        pa[0] = *(const f16x8*)(Pw0 + l15 * 40 + g * 8);
        pa[1] = *(const f16x8*)(Pw0 + (16 + l15) * 40 + g * 8);

        // ---- PV: swizzled conflict-free qT reads ----
        #pragma unroll
        for (int dt = 0; dt < 16; dt++) {
            f16x8 bq = *(const f16x8*)(qTb_l + qTbase + dt * 512);
            qa[dt][0] = __builtin_amdgcn_mfma_f32_16x16x32_f16(bq, pa[0], qa[dt][0], 0, 0, 0);
            qa[dt][1] = __builtin_amdgcn_mfma_f32_16x16x32_f16(bq, pa[1], qa[dt][1], 0, 0, 0);
        }

        __builtin_amdgcn_sched_barrier(0);
        __builtin_amdgcn_s_barrier();
        cur ^= 1;
    }
    #undef STAGE_ATTN

    // ---- finalize: divide by per-x sum (per-lane), store fp16 q_a ----
    #pragma unroll
    for (int xs = 0; xs < 2; xs++) {
        float s_tot = s_run[xs] + __shfl_xor(s_run[xs], 16);
        s_tot = s_tot + __shfl_xor(s_tot, 32);
        float inv = 1.0f / s_tot;
        uint16_t* outp = qa16 + ((long)b * JXX + xw + xs * 16 + l15) * DDD;
        #pragma unroll
        for (int dt = 0; dt < 16; dt++) {
            f16x4 v;
            v[0] = (_Float16)(qa[dt][xs][0] * inv);
            v[1] = (_Float16)(qa[dt][xs][1] * inv);
            v[2] = (_Float16)(qa[dt][xs][2] * inv);
            v[3] = (_Float16)(qa[dt][xs][3] * inv);
            *(f16x4*)(outp + dt * 16 + g * 4) = v;
        }
    }
}

// ---------------- fused SFU v4 (unchanged): W via LDS double-buffer pipeline ----------------
__global__ __launch_bounds__(256, 3) void k_sfu(
    const float* __restrict__ cg,
    const uint16_t* __restrict__ qa16,
    const uint16_t* __restrict__ WrP,
    const uint16_t* __restrict__ WgP,
    const float* __restrict__ Brb,
    const float* __restrict__ Bgb,
    float* __restrict__ outg)
{
    __shared__ __align__(16) uint16_t c_lds[64 * 72];
    __shared__ __align__(16) uint16_t qa_lds[64 * 72];
    __shared__ __align__(16) uint16_t wbuf[2][8192];

    const int t = threadIdx.x;
    const int wave = t >> 6;
    const int lane = t & 63;
    const int l15 = lane & 15, g = lane >> 4;
    const int mw = wave & 1, nw = wave >> 1;
    const long m0 = (long)blockIdx.x * 64;
    const int n0 = blockIdx.y * 128, ny0 = blockIdx.y * 8;

    const f32x4 fzero = {0.f, 0.f, 0.f, 0.f};
    f32x4 accR[2][4], accG[2][4];
    #pragma unroll
    for (int a = 0; a < 2; a++)
        #pragma unroll
        for (int bq = 0; bq < 4; bq++) { accR[a][bq] = fzero; accG[a][bq] = fzero; }

    #define STAGE_W(bufp, kt)                                                     \
        {                                                                         \
            _Pragma("unroll")                                                     \
            for (int i = 0; i < 4; i++) {                                         \
                int s = i * 4 + wave;                                             \
                const uint16_t* src = (s < 8)                                     \
                    ? WrP + ((long)((kt) * 16 + ny0 + s) * 64 + lane) * 8         \
                    : WgP + ((long)((kt) * 16 + ny0 + s - 8) * 64 + lane) * 8;    \
                gload_lds16(src, (bufp) + i * 2048 + wave * 512);                 \
            }                                                                     \
        }

    int cur = 0;
    STAGE_W(&wbuf[0][0], 0);

    #pragma unroll
    for (int dt = 0; dt < 4; dt++) {
        __syncthreads();
        #pragma unroll
        for (int i = 0; i < 2; i++) {
            int e = t + 256 * i;
            int row = e >> 3, c8 = e & 7;
            const float* p = cg + (m0 + row) * DDD + dt * 64 + c8 * 8;
            float4 v0 = *(const float4*)p;
            float4 v1 = *(const float4*)(p + 4);
            f16x8 f;
            f[0] = (_Float16)v0.x; f[1] = (_Float16)v0.y; f[2] = (_Float16)v0.z; f[3] = (_Float16)v0.w;
            f[4] = (_Float16)v1.x; f[5] = (_Float16)v1.y; f[6] = (_Float16)v1.z; f[7] = (_Float16)v1.w;
            *(f16x8*)(c_lds + row * 72 + c8 * 8) = f;
            *(f16x8*)(qa_lds + row * 72 + c8 * 8) =
                *(const f16x8*)(qa16 + (m0 + row) * DDD + dt * 64 + c8 * 8);
        }
        __syncthreads();
        #pragma unroll
        for (int kb = 0; kb < 2; kb++) {
            f16x8 af[4][2];
            #pragma unroll
            for (int mf = 0; mf < 2; mf++) {
                int row = mw * 32 + mf * 16 + l15;
                f16x8 cf = *(const f16x8*)(c_lds + row * 72 + kb * 32 + g * 8);
                f16x8 qf = *(const f16x8*)(qa_lds + row * 72 + kb * 32 + g * 8);
                af[0][mf] = cf;
                af[1][mf] = qf;
                af[2][mf] = cf * qf;
                af[3][mf] = cf - qf;
            }
            #pragma unroll
            for (int comp = 0; comp < 4; comp++) {
                const int step = (dt * 2 + kb) * 4 + comp;
                if (step < 31) {
                    const int ns = step + 1;
                    const int ndt = ns >> 3, nkb = (ns >> 2) & 1, ncomp = ns & 3;
                    const int nkt = ncomp * 8 + ndt * 2 + nkb;
                    STAGE_W(&wbuf[cur ^ 1][0], nkt);
                    asm volatile("s_waitcnt vmcnt(4)" ::: "memory");
                } else {
                    asm volatile("s_waitcnt vmcnt(0)" ::: "memory");
                }
                __builtin_amdgcn_s_barrier();
                __builtin_amdgcn_sched_barrier(0);
                const uint16_t* Wb = &wbuf[cur][0];
                #pragma unroll
                for (int nt = 0; nt < 4; nt++) {
                    f16x8 br = *(const f16x8*)(Wb + (nw * 4 + nt) * 512 + lane * 8);
                    f16x8 bg = *(const f16x8*)(Wb + 4096 + (nw * 4 + nt) * 512 + lane * 8);
                    accR[0][nt] = __builtin_amdgcn_mfma_f32_16x16x32_f16(af[comp][0], br, accR[0][nt], 0, 0, 0);
                    accR[1][nt] = __builtin_amdgcn_mfma_f32_16x16x32_f16(af[comp][1], br, accR[1][nt], 0, 0, 0);
                    accG[0][nt] = __builtin_amdgcn_mfma_f32_16x16x32_f16(af[comp][0], bg, accG[0][nt], 0, 0, 0);
                    accG[1][nt] = __builtin_amdgcn_mfma_f32_16x16x32_f16(af[comp][1], bg, accG[1][nt], 0, 0, 0);
                }
                __builtin_amdgcn_sched_barrier(0);
                __builtin_amdgcn_s_barrier();
                cur ^= 1;
            }
        }
    }
    #undef STAGE_W

    #pragma unroll
    for (int nt = 0; nt < 4; nt++) {
        int n = n0 + nw * 64 + nt * 16 + l15;
        float br = Brb[n], bg = Bgb[n];
        #pragma unroll
        for (int mf = 0; mf < 2; mf++) {
            long rowb = m0 + mw * 32 + mf * 16 + g * 4;
            #pragma unroll
            for (int r = 0; r < 4; r++) {
                float pr = accR[mf][nt][r] + br;
                float pg = accG[mf][nt][r] + bg;
                float x = fminf(fmaxf(pr, -30.f), 30.f);
                float e2 = __expf(2.f * x);
                float rr = (e2 - 1.f) / (e2 + 1.f);
                float gv = 1.0f / (1.0f + __expf(-pg));
                float cv = cg[(rowb + r) * DDD + n];
                outg[(rowb + r) * DDD + n] = gv * rr + (1.f - gv) * cv;
            }
        }
    }
}

extern "C" void kernel_launch(void* const* d_in, const int* in_sizes, int n_in,
                              void* d_out, int out_size, void* d_ws, size_t ws_size,
                              hipStream_t stream) {
    const float* c  = (const float*)d_in[0];
    const float* q  = (const float*)d_in[1];
    const float* Wr = (const float*)d_in[2];
    const float* Br = (const float*)d_in[3];
    const float* Wg = (const float*)d_in[4];
    const float* Bg = (const float*)d_in[5];
    const void* cmask = d_in[6];
    const void* qmask = d_in[7];

    char* ws = (char*)d_ws;
    uint16_t* qS    = (uint16_t*)(ws + 0);          //  4,194,304 B
    uint16_t* qTS   = (uint16_t*)(ws + 4194304);    //  4,194,304 B
    uint16_t* qa16  = (uint16_t*)(ws + 8388608);    // 33,554,432 B
    uint16_t* WrP   = (uint16_t*)(ws + 41943040);   //    524,288 B
    uint16_t* WgP   = (uint16_t*)(ws + 42467328);   //    524,288 B
    uint8_t*  cm8   = (uint8_t*)(ws + 42991616);    //     65,536 B
    uint8_t*  qm8   = (uint8_t*)(ws + 43057152);    //      8,192 B
    (void)in_sizes; (void)n_in; (void)out_size; (void)ws_size;

    k_mask<<<dim3((NB * JXX + 255) / 256), dim3(256), 0, stream>>>(cmask, qmask, cm8, qm8);
    k_prep_q<<<dim3(8, 4, NB), dim3(256), 0, stream>>>(q, qS, qTS);
    k_prep_w<<<dim3(32, 2), dim3(256), 0, stream>>>(Wr, Wg, WrP, WgP);
    k_attn<<<dim3(JXX / 128, NB), dim3(256), 0, stream>>>(c, qS, qTS, cm8, qm8, qa16);
    k_sfu<<<dim3((NB * JXX) / 64, 2), dim3(256), 0, stream>>>(
        c, qa16, WrP, WgP, Br, Bg, (float*)d_out);
}